// Round 1
// baseline (9784.112 us; speedup 1.0000x reference)
//
#include <hip/hip_runtime.h>
#include <math.h>

#define HID 256
#define TT  256
#define BT  4      // batch rows per block
#define NBLK 128   // 512 / BT

// ---------------------------------------------------------------------------
// Pre-pass: W [1024][K] row-major  ->  A [K][256][4]  (gate-interleaved, k-major)
// A[kk*1024 + k*4 + g] = W[(g*256+k)*K + kk]
// ---------------------------------------------------------------------------
__global__ void transpose_gi(const float* __restrict__ W, float* __restrict__ A, int K) {
    int idx = blockIdx.x * 256 + threadIdx.x;
    if (idx < K * 1024) {
        int kk = idx >> 10;
        int r  = idx & 1023;
        int k  = r >> 2;
        int g  = r & 3;
        A[idx] = W[(g * 256 + k) * K + kk];
    }
}

__device__ __forceinline__ float sigf(float x) {
    return 1.0f / (1.0f + __expf(-x));
}
__device__ __forceinline__ float tanhfast(float x) {
    // 1 - 2/(e^{2x}+1); saturates correctly at +/-inf of __expf
    return 1.0f - 2.0f / (__expf(2.0f * x) + 1.0f);
}

__device__ __forceinline__ void fma4(float4& a, float w, const float4& h) {
    a.x += w * h.x; a.y += w * h.y; a.z += w * h.z; a.w += w * h.w;
}

// ---------------------------------------------------------------------------
// Fused 2-layer LSTM. Each block owns BT=4 batch rows for the whole sequence.
// Thread k (0..255) owns hidden index k: 4 gates x 4 batch rows of accumulators.
// Inner iter: 1 coalesced dwordx4 (W, 4 gates at (kk,k)) + 1 broadcast b128
// (h[kk] for 4 rows) + 16 fp32 FMAs.
// ---------------------------------------------------------------------------
__global__ __launch_bounds__(256)
void lstm2_fused(const float* __restrict__ x,
                 const float* __restrict__ Aih0, const float* __restrict__ Ahh0,
                 const float* __restrict__ Aih1, const float* __restrict__ Ahh1,
                 const float* __restrict__ bih0, const float* __restrict__ bhh0,
                 const float* __restrict__ bih1, const float* __restrict__ bhh1,
                 const float* __restrict__ Wlin, const float* __restrict__ blin,
                 float* __restrict__ out)
{
    __shared__ float4 sh0[HID];        // layer-0 h state, [kk] -> 4 batch rows
    __shared__ float4 sh1[HID];        // layer-1 h state
    __shared__ float4 sx[TT * 10];     // x staged: [t*10+i] -> 4 batch rows
    __shared__ float4 red[4];          // head reduction

    const int k  = threadIdx.x;
    const int b0 = blockIdx.x * BT;

    // ---- stage x for this block's 4 rows (contiguous 10240 floats) ----
    const float* xblk = x + (size_t)b0 * (TT * 10);
    float* sxf = (float*)sx;
    #pragma unroll
    for (int n = 0; n < 40; ++n) {
        int e = k + n * 256;          // 0..10239
        int b = e / 2560;
        int r = e - b * 2560;
        sxf[r * 4 + b] = xblk[e];
    }

    sh0[k] = make_float4(0.f, 0.f, 0.f, 0.f);
    sh1[k] = make_float4(0.f, 0.f, 0.f, 0.f);
    float4 c0 = make_float4(0.f, 0.f, 0.f, 0.f);
    float4 c1 = make_float4(0.f, 0.f, 0.f, 0.f);

    float bias0[4], bias1[4];
    #pragma unroll
    for (int g = 0; g < 4; ++g) {
        bias0[g] = bih0[g * HID + k] + bhh0[g * HID + k];
        bias1[g] = bih1[g * HID + k] + bhh1[g * HID + k];
    }
    const float wl = Wlin[k];

    const float4* A0i = (const float4*)Aih0;  // [i*256 + k]
    const float4* A0h = (const float4*)Ahh0;  // [kk*256 + k]
    const float4* A1i = (const float4*)Aih1;
    const float4* A1h = (const float4*)Ahh1;

    __syncthreads();

    for (int t = 0; t < TT; ++t) {
        // ================= layer 0 =================
        float4 acc[4];
        #pragma unroll
        for (int g = 0; g < 4; ++g)
            acc[g] = make_float4(bias0[g], bias0[g], bias0[g], bias0[g]);

        // input contribution (I = 10)
        #pragma unroll
        for (int i = 0; i < 10; ++i) {
            float4 xv = sx[t * 10 + i];
            float4 w  = A0i[i * 256 + k];
            fma4(acc[0], w.x, xv); fma4(acc[1], w.y, xv);
            fma4(acc[2], w.z, xv); fma4(acc[3], w.w, xv);
        }
        // recurrent contribution
        #pragma unroll 4
        for (int kk = 0; kk < HID; ++kk) {
            float4 h4 = sh0[kk];
            float4 w  = A0h[kk * 256 + k];
            fma4(acc[0], w.x, h4); fma4(acc[1], w.y, h4);
            fma4(acc[2], w.z, h4); fma4(acc[3], w.w, h4);
        }
        __syncthreads();   // everyone done READING sh0

        float4 hn;
        c0.x = sigf(acc[1].x) * c0.x + sigf(acc[0].x) * tanhfast(acc[2].x);
        c0.y = sigf(acc[1].y) * c0.y + sigf(acc[0].y) * tanhfast(acc[2].y);
        c0.z = sigf(acc[1].z) * c0.z + sigf(acc[0].z) * tanhfast(acc[2].z);
        c0.w = sigf(acc[1].w) * c0.w + sigf(acc[0].w) * tanhfast(acc[2].w);
        hn.x = sigf(acc[3].x) * tanhfast(c0.x);
        hn.y = sigf(acc[3].y) * tanhfast(c0.y);
        hn.z = sigf(acc[3].z) * tanhfast(c0.z);
        hn.w = sigf(acc[3].w) * tanhfast(c0.w);
        sh0[k] = hn;
        __syncthreads();   // new sh0 visible

        // ================= layer 1 =================
        #pragma unroll
        for (int g = 0; g < 4; ++g)
            acc[g] = make_float4(bias1[g], bias1[g], bias1[g], bias1[g]);

        #pragma unroll 4
        for (int kk = 0; kk < HID; ++kk) {
            float4 h4 = sh0[kk];                // layer-0 output, this step
            float4 w  = A1i[kk * 256 + k];
            fma4(acc[0], w.x, h4); fma4(acc[1], w.y, h4);
            fma4(acc[2], w.z, h4); fma4(acc[3], w.w, h4);
        }
        #pragma unroll 4
        for (int kk = 0; kk < HID; ++kk) {
            float4 h4 = sh1[kk];                // layer-1 h, previous step
            float4 w  = A1h[kk * 256 + k];
            fma4(acc[0], w.x, h4); fma4(acc[1], w.y, h4);
            fma4(acc[2], w.z, h4); fma4(acc[3], w.w, h4);
        }
        __syncthreads();   // everyone done READING sh1 (and sh0)

        c1.x = sigf(acc[1].x) * c1.x + sigf(acc[0].x) * tanhfast(acc[2].x);
        c1.y = sigf(acc[1].y) * c1.y + sigf(acc[0].y) * tanhfast(acc[2].y);
        c1.z = sigf(acc[1].z) * c1.z + sigf(acc[0].z) * tanhfast(acc[2].z);
        c1.w = sigf(acc[1].w) * c1.w + sigf(acc[0].w) * tanhfast(acc[2].w);
        hn.x = sigf(acc[3].x) * tanhfast(c1.x);
        hn.y = sigf(acc[3].y) * tanhfast(c1.y);
        hn.z = sigf(acc[3].z) * tanhfast(c1.z);
        hn.w = sigf(acc[3].w) * tanhfast(c1.w);
        sh1[k] = hn;
        __syncthreads();
    }

    // ================= head: y[b] = sum_k h1[b,k]*Wlin[k] + blin =================
    float4 part = sh1[k];
    part.x *= wl; part.y *= wl; part.z *= wl; part.w *= wl;
    #pragma unroll
    for (int off = 32; off > 0; off >>= 1) {
        part.x += __shfl_down(part.x, off, 64);
        part.y += __shfl_down(part.y, off, 64);
        part.z += __shfl_down(part.z, off, 64);
        part.w += __shfl_down(part.w, off, 64);
    }
    if ((k & 63) == 0) red[k >> 6] = part;
    __syncthreads();
    if (k < BT) {
        const float* rf = (const float*)red;
        float s = rf[0 * 4 + k] + rf[1 * 4 + k] + rf[2 * 4 + k] + rf[3 * 4 + k];
        out[b0 + k] = s + blin[0];
    }
}

// ---------------------------------------------------------------------------
extern "C" void kernel_launch(void* const* d_in, const int* in_sizes, int n_in,
                              void* d_out, int out_size, void* d_ws, size_t ws_size,
                              hipStream_t stream) {
    const float* x     = (const float*)d_in[0];
    const float* W_ih0 = (const float*)d_in[1];
    const float* W_hh0 = (const float*)d_in[2];
    const float* b_ih0 = (const float*)d_in[3];
    const float* b_hh0 = (const float*)d_in[4];
    const float* W_ih1 = (const float*)d_in[5];
    const float* W_hh1 = (const float*)d_in[6];
    const float* b_ih1 = (const float*)d_in[7];
    const float* b_hh1 = (const float*)d_in[8];
    const float* W_lin = (const float*)d_in[9];
    const float* b_lin = (const float*)d_in[10];
    float* out = (float*)d_out;

    float* A     = (float*)d_ws;
    float* Ahh0  = A;                   // 256*1024
    float* Aih1  = A + 262144;          // 256*1024
    float* Ahh1  = A + 524288;          // 256*1024
    float* Aih0  = A + 786432;          // 10*1024

    transpose_gi<<<1024, 256, 0, stream>>>(W_hh0, Ahh0, 256);
    transpose_gi<<<1024, 256, 0, stream>>>(W_ih1, Aih1, 256);
    transpose_gi<<<1024, 256, 0, stream>>>(W_hh1, Ahh1, 256);
    transpose_gi<<<40,   256, 0, stream>>>(W_ih0, Aih0, 10);

    lstm2_fused<<<NBLK, 256, 0, stream>>>(
        x, Aih0, Ahh0, Aih1, Ahh1,
        b_ih0, b_hh0, b_ih1, b_hh1,
        W_lin, b_lin, out);
}